// Round 8
// baseline (217.535 us; speedup 1.0000x reference)
//
#include <hip/hip_runtime.h>

// VQ-VAE codebook quantization — R8: barrier-free register GEMM (no K-loop LDS).
//   x: [32, 256, 32, 32] f32 -> z: [N=32768, D=256]; W: [1024, 256] f32
//   idx[n] = argmin_k (|w_k|^2 - 2 z_n.w_k)
//   bf16 3-term split (wh·zh + wl·zh + wh·zl), error <= ~2e-4 << MARGIN;
//   rows with (second - best) <= MARGIN exactly rescored in fp32.
// Outputs flat f32: z_q (8388608), idx-as-float (32768), loss (1)

#define N_ROWS 32768
#define K_CODES 1024
#define D_DIM 256
#define MARGIN 0.015625f

using f32x4  = __attribute__((ext_vector_type(4))) float;
using bf16x8 = __attribute__((ext_vector_type(8))) short;

__device__ __forceinline__ unsigned int rne_bf16(float f) {
    unsigned int u = __float_as_uint(f);
    return (u + 0x7FFFu + ((u >> 16) & 1u)) >> 16;   // round-to-nearest-even bf16 bits
}

// ---------------- fused: wsq (exact fp32) + W->bf16 hi/lo + acc zeroing ----------------
__global__ void prep_kernel(const float* __restrict__ W, float* __restrict__ wsq,
                            unsigned short* __restrict__ Wh, unsigned short* __restrict__ Wl,
                            float* __restrict__ loss_acc, int* __restrict__ scount) {
    int p = blockIdx.x * 256 + threadIdx.x;    // 65536 float4s
    if (p == 0) { *loss_acc = 0.0f; *scount = 0; }
    float4 v = *(const float4*)(W + (size_t)p * 4);
    unsigned int h0 = rne_bf16(v.x), h1 = rne_bf16(v.y), h2 = rne_bf16(v.z), h3 = rne_bf16(v.w);
    float f0 = __uint_as_float(h0 << 16), f1 = __uint_as_float(h1 << 16);
    float f2 = __uint_as_float(h2 << 16), f3 = __uint_as_float(h3 << 16);
    unsigned int l0 = rne_bf16(v.x - f0), l1 = rne_bf16(v.y - f1);
    unsigned int l2 = rne_bf16(v.z - f2), l3 = rne_bf16(v.w - f3);
    *(uint2*)(Wh + (size_t)p * 4) = make_uint2(h0 | (h1 << 16), h2 | (h3 << 16));
    *(uint2*)(Wl + (size_t)p * 4) = make_uint2(l0 | (l1 << 16), l2 | (l3 << 16));
    if (p < K_CODES) {
        const float4* w4 = (const float4*)(W + (size_t)p * D_DIM);
        float s = 0.0f;
#pragma unroll 8
        for (int i = 0; i < D_DIM / 4; i++) {
            float4 q = w4[i];
            s += q.x * q.x + q.y * q.y + q.z * q.z + q.w * q.w;
        }
        wsq[p] = s;
    }
}

// ---------------- x -> Zh/Zl bf16 [n][d] (transpose via LDS) ----------------
__global__ void convz_kernel(const float* __restrict__ x, unsigned short* __restrict__ Zh,
                             unsigned short* __restrict__ Zl) {
    __shared__ float tile[64][65];
    const int bid = blockIdx.x;            // 2048 = 32 b * 4 dblk * 16 hwblk
    const int b = bid >> 6, dblk = (bid >> 4) & 3, hwblk = bid & 15;
    const int t = threadIdx.x;
    const float* xb = x + ((size_t)(b * 256 + dblk * 64)) * 1024 + hwblk * 64;
#pragma unroll
    for (int i = 0; i < 4; i++) {
        int dl = i * 16 + (t >> 4);
        int hl = (t & 15) * 4;
        float4 v = *(const float4*)(xb + (size_t)dl * 1024 + hl);
        tile[dl][hl] = v.x; tile[dl][hl + 1] = v.y; tile[dl][hl + 2] = v.z; tile[dl][hl + 3] = v.w;
    }
    __syncthreads();
    const int n0 = b * 1024 + hwblk * 64, d0 = dblk * 64;
#pragma unroll
    for (int j = 0; j < 2; j++) {
        int r = j * 32 + (t >> 3);
        int dc = (t & 7) * 8;
        unsigned int hi[8], lo[8];
#pragma unroll
        for (int q = 0; q < 8; q++) {
            float f = tile[dc + q][r];
            hi[q] = rne_bf16(f);
            lo[q] = rne_bf16(f - __uint_as_float(hi[q] << 16));
        }
        uint4 hp = make_uint4(hi[0] | (hi[1] << 16), hi[2] | (hi[3] << 16),
                              hi[4] | (hi[5] << 16), hi[6] | (hi[7] << 16));
        uint4 lp = make_uint4(lo[0] | (lo[1] << 16), lo[2] | (lo[3] << 16),
                              lo[4] | (lo[5] << 16), lo[6] | (lo[7] << 16));
        *(uint4*)(Zh + (size_t)(n0 + r) * 256 + d0 + dc) = hp;
        *(uint4*)(Zl + (size_t)(n0 + r) * 256 + d0 + dc) = lp;
    }
}

// ---------------- MFMA distance GEMM + best/second argmin (barrier-free) ----------------
// Block: 128 codes x 128 zrows; 4 waves (wm,wn); per-wave 64x64 = 4x4 frags 16x16x32 bf16.
// NO LDS in the K-loop: A (Wh/Wl) AND B (Zh/Zl) fragments are loaded directly from
// global (L2-hot: W 2 MB + z-tile 128 KB per XCD via the XCD-chunked swizzle) into
// double-buffered registers, one 32-dim chunk ahead. Waves are fully independent —
// no __syncthreads, no vmcnt choreography; the compiler's own waitcnt scheduling
// pipelines loads under the 48 MFMAs/chunk. Term-major passes (hh, lh, hl) keep
// consecutive MFMAs independent; per-acc accumulation order unchanged vs R5-R7.
__launch_bounds__(256, 2)
__global__ void mm_argmin_kernel(const unsigned short* __restrict__ Zh,
                                 const unsigned short* __restrict__ Zl,
                                 const unsigned short* __restrict__ Wh,
                                 const unsigned short* __restrict__ Wl,
                                 const float* __restrict__ wsq, float* __restrict__ pws) {
    __shared__ float red[2][128][3];        // 3 KB (epilogue only)

    const int t = threadIdx.x;
    const int w = t >> 6, lane = t & 63;
    const int wm = w & 1, wn = w >> 1;
    // XCD-chunked bijective decode (2048 blocks, 8 XCDs round-robin by blockIdx&7)
    const int g  = blockIdx.x & 7;          // XCD
    const int s  = blockIdx.x >> 3;         // per-XCD sequence 0..255
    const int cb = s & 7;                   // 8 consecutive same-XCD slots share nb
    const int nb = g * 32 + (s >> 3);
    const int c0 = cb * 128, n0 = nb * 128;

    const int lrow = lane & 15;             // fragment row within 16
    const int lk   = (lane >> 4) << 3;      // fragment k-offset (ushorts)
    const size_t aoff = ((size_t)(c0 + wm * 64 + lrow) << 8) + lk;   // A frag base
    const size_t boff = ((size_t)(n0 + wn * 64 + lrow) << 8) + lk;   // B frag base

    f32x4 acc[4][4];
#pragma unroll
    for (int i = 0; i < 4; i++)
#pragma unroll
        for (int j = 0; j < 4; j++) acc[i][j] = (f32x4){0.f, 0.f, 0.f, 0.f};

    bf16x8 Ah[2][4], Al[2][4], Bh[2][4], Bl[2][4];   // 128 VGPR operand dbuf

#define LOAD_OPS(set_, d0_)                                                   \
    _Pragma("unroll")                                                         \
    for (int f_ = 0; f_ < 4; f_++) {                                          \
        Ah[set_][f_] = *(const bf16x8*)(Wh + aoff + f_ * 4096 + (d0_));       \
        Al[set_][f_] = *(const bf16x8*)(Wl + aoff + f_ * 4096 + (d0_));       \
        Bh[set_][f_] = *(const bf16x8*)(Zh + boff + f_ * 4096 + (d0_));       \
        Bl[set_][f_] = *(const bf16x8*)(Zl + boff + f_ * 4096 + (d0_));       \
    }

    LOAD_OPS(0, 0);

#pragma unroll
    for (int ch = 0; ch < 8; ch++) {        // full unroll -> all set indices static
        const int pb = ch & 1;
        if (ch < 7) LOAD_OPS(pb ^ 1, (ch + 1) * 32);   // 16 loads fly under the MFMAs

        __builtin_amdgcn_s_setprio(1);
        // pass 1: hh — 16 independent MFMAs
#pragma unroll
        for (int mf = 0; mf < 4; mf++)
#pragma unroll
            for (int nf = 0; nf < 4; nf++)
                acc[mf][nf] = __builtin_amdgcn_mfma_f32_16x16x32_bf16(Ah[pb][mf], Bh[pb][nf], acc[mf][nf], 0, 0, 0);
        // pass 2: lh
#pragma unroll
        for (int mf = 0; mf < 4; mf++)
#pragma unroll
            for (int nf = 0; nf < 4; nf++)
                acc[mf][nf] = __builtin_amdgcn_mfma_f32_16x16x32_bf16(Al[pb][mf], Bh[pb][nf], acc[mf][nf], 0, 0, 0);
        // pass 3: hl
#pragma unroll
        for (int mf = 0; mf < 4; mf++)
#pragma unroll
            for (int nf = 0; nf < 4; nf++)
                acc[mf][nf] = __builtin_amdgcn_mfma_f32_16x16x32_bf16(Ah[pb][mf], Bl[pb][nf], acc[mf][nf], 0, 0, 0);
        __builtin_amdgcn_s_setprio(0);
    }
#undef LOAD_OPS

    // ---- epilogue: scores + best/second argmin
    // lane's codes: c0 + wm*64 + mf*16 + (lane>>4)*4 + r ; zrow col = lane&15 (per nf)
    float ws16[16];
#pragma unroll
    for (int mf = 0; mf < 4; mf++)
#pragma unroll
        for (int r = 0; r < 4; r++)
            ws16[mf * 4 + r] = wsq[c0 + wm * 64 + mf * 16 + ((lane >> 4) << 2) + r];

    float b1[4], b2[4]; int i1[4];
#pragma unroll
    for (int nf = 0; nf < 4; nf++) {
        b1[nf] = 1e30f; b2[nf] = 1e30f; i1[nf] = 0;
#pragma unroll
        for (int mf = 0; mf < 4; mf++)
#pragma unroll
            for (int r = 0; r < 4; r++) {
                float s2 = ws16[mf * 4 + r] - 2.0f * acc[mf][nf][r];
                int code = c0 + wm * 64 + mf * 16 + ((lane >> 4) << 2) + r;
                if (s2 < b1[nf]) { b2[nf] = b1[nf]; b1[nf] = s2; i1[nf] = code; }
                else if (s2 < b2[nf]) b2[nf] = s2;
            }
    }
    // merge across the 4 k-lane-groups holding the same zrow (lane&15)
#pragma unroll
    for (int off = 16; off <= 32; off <<= 1) {
#pragma unroll
        for (int nf = 0; nf < 4; nf++) {
            float ob1 = __shfl_xor(b1[nf], off);
            float ob2 = __shfl_xor(b2[nf], off);
            int   oi1 = __shfl_xor(i1[nf], off);
            float nb2 = fminf(fminf(b2[nf], ob2), fmaxf(b1[nf], ob1));
            if (ob1 < b1[nf] || (ob1 == b1[nf] && oi1 < i1[nf])) { b1[nf] = ob1; i1[nf] = oi1; }
            b2[nf] = nb2;
        }
    }
    if ((lane >> 4) == 0) {
#pragma unroll
        for (int nf = 0; nf < 4; nf++) {
            int zr = wn * 64 + nf * 16 + (lane & 15);
            red[wm][zr][0] = b1[nf];
            red[wm][zr][1] = __int_as_float(i1[nf]);
            red[wm][zr][2] = b2[nf];
        }
    }
    __syncthreads();
    if (t < 128) {
        float a1 = red[0][t][0], ai = red[0][t][1], a2 = red[0][t][2];
        float c1 = red[1][t][0], ci = red[1][t][1], c2 = red[1][t][2];
        float m2 = fminf(fminf(a2, c2), fmaxf(a1, c1));
        float m1 = a1, mi = ai;
        if (c1 < a1) { m1 = c1; mi = ci; }   // tie keeps wm0 (lower codes)
        float* dst = pws + ((size_t)(n0 + t) * 8 + cb) * 3;
        dst[0] = m1; dst[1] = mi; dst[2] = m2;
    }
}

// ---------------- combine 8 code-block partials; flag suspects ----------------
__global__ void combine_kernel(const float* __restrict__ pws, float* __restrict__ out_idx_f,
                               int* __restrict__ ws_idx, int* __restrict__ scount,
                               int* __restrict__ slist) {
    int n = blockIdx.x * 256 + threadIdx.x;
    float b1 = 1e30f, bi = 0.f, b2 = 1e30f;
    const float* e = pws + (size_t)n * 24;
#pragma unroll
    for (int cbk = 0; cbk < 8; cbk++) {
        float e1 = e[cbk * 3 + 0], ei = e[cbk * 3 + 1], e2 = e[cbk * 3 + 2];
        float m2 = fminf(fminf(b2, e2), fmaxf(b1, e1));
        if (e1 < b1) { b1 = e1; bi = ei; }   // ties keep earlier cb (lower codes)
        b2 = m2;
    }
    int idx = __float_as_int(bi);
    ws_idx[n] = idx;
    out_idx_f[n] = (float)idx;
    if (b2 - b1 <= MARGIN) {
        int pos = atomicAdd(scount, 1);
        slist[pos] = n;
    }
}

// ---------------- exact fp32 rescore of suspect rows ----------------
__global__ void rescore_kernel(const float* __restrict__ x, const float* __restrict__ W,
                               const float* __restrict__ wsq, const int* __restrict__ scount,
                               const int* __restrict__ slist, float* __restrict__ out_idx_f,
                               int* __restrict__ ws_idx) {
    __shared__ float zrow[256];
    __shared__ float rv[256];
    __shared__ int   ri[256];
    const int cnt = *scount;
    for (int s = blockIdx.x; s < cnt; s += gridDim.x) {
        const int n = slist[s];
        const int b = n >> 10, hw = n & 1023;
        __syncthreads();
        zrow[threadIdx.x] = x[(((size_t)(b * 256 + threadIdx.x)) << 10) + hw];
        __syncthreads();
        float best = 1e30f; int bidx = 0;
        for (int j = 0; j < 4; j++) {
            const int k = threadIdx.x + j * 256;    // ascending per thread
            const float4* wr = (const float4*)(W + (size_t)k * 256);
            float dot = 0.f;
#pragma unroll 16
            for (int q = 0; q < 64; q++) {
                float4 wv = wr[q];
                float4 zv = *(const float4*)&zrow[q * 4];
                dot = fmaf(wv.x, zv.x, dot); dot = fmaf(wv.y, zv.y, dot);
                dot = fmaf(wv.z, zv.z, dot); dot = fmaf(wv.w, zv.w, dot);
            }
            float sc = wsq[k] - 2.f * dot;
            if (sc < best) { best = sc; bidx = k; }
        }
        rv[threadIdx.x] = best; ri[threadIdx.x] = bidx;
        __syncthreads();
        for (int st = 128; st > 0; st >>= 1) {
            if ((int)threadIdx.x < st) {
                float ov = rv[threadIdx.x + st]; int oi = ri[threadIdx.x + st];
                if (ov < rv[threadIdx.x] || (ov == rv[threadIdx.x] && oi < ri[threadIdx.x])) {
                    rv[threadIdx.x] = ov; ri[threadIdx.x] = oi;
                }
            }
            __syncthreads();
        }
        if (threadIdx.x == 0) { ws_idx[n] = ri[0]; out_idx_f[n] = (float)ri[0]; }
    }
}

// ---------------- fallback fp32 argmin (proven R1 kernel, used if ws too small) ----------------
#define FROWS 64
#define FKT 256
#define FDT 32
#define FKTP 260

__launch_bounds__(256, 3)
__global__ void argmin_f32_kernel(const float* __restrict__ x, const float* __restrict__ W,
                                  const float* __restrict__ wsq,
                                  float* __restrict__ out_idx_f, int* __restrict__ ws_idx) {
    __shared__ float zT[FDT][FROWS];
    __shared__ float wT[FDT][FKTP];
    const int t = threadIdx.x;
    const int lane = t & 63;
    const int wv = t >> 6;
    const int tc = t & 31;
    const int tr = t >> 5;
    const int tr8 = tr * 8, tc4 = tc * 4;
    const int n0 = blockIdx.x * FROWS;
    const int b = n0 >> 10;
    const int hw0 = n0 & 1023;
    const size_t xbase = (size_t)b * D_DIM * 1024;
    float rmin[8]; int ridx[8];
#pragma unroll
    for (int i = 0; i < 8; i++) { rmin[i] = 1e30f; ridx[i] = 0; }
#pragma unroll 1
    for (int k0 = 0; k0 < K_CODES; k0 += FKT) {
        float acc[8][8] = {{0.f}};
#pragma unroll 1
        for (int d0 = 0; d0 < D_DIM; d0 += FDT) {
#pragma unroll
            for (int i = 0; i < 2; i++) {
                int dl0 = wv * 8 + i * 4;
                const float* src = x + xbase + ((size_t)(d0 + dl0 + (lane >> 4)) << 10)
                                 + hw0 + ((lane & 15) << 2);
                __builtin_amdgcn_global_load_lds(
                    (const __attribute__((address_space(1))) void*)src,
                    (__attribute__((address_space(3))) void*)&zT[dl0][0], 16, 0, 0);
            }
#pragma unroll
            for (int i = 0; i < 8; i++) {
                int e = t + i * 256;
                int kk = e >> 3, dg = e & 7;
                float4 v = *(const float4*)(W + (size_t)(k0 + kk) * D_DIM + d0 + dg * 4);
                wT[dg * 4 + 0][kk] = v.x; wT[dg * 4 + 1][kk] = v.y;
                wT[dg * 4 + 2][kk] = v.z; wT[dg * 4 + 3][kk] = v.w;
            }
            __syncthreads();
#pragma unroll 4
            for (int d = 0; d < FDT; d++) {
                float zr[8], wc[8];
                *(float4*)&zr[0] = *(const float4*)&zT[d][tr8];
                *(float4*)&zr[4] = *(const float4*)&zT[d][tr8 + 4];
                *(float4*)&wc[0] = *(const float4*)&wT[d][tc4];
                *(float4*)&wc[4] = *(const float4*)&wT[d][tc4 + 128];
#pragma unroll
                for (int i = 0; i < 8; i++)
#pragma unroll
                    for (int j = 0; j < 8; j++)
                        acc[i][j] = fmaf(zr[i], wc[j], acc[i][j]);
            }
            __syncthreads();
        }
#pragma unroll
        for (int g = 0; g < 2; g++)
#pragma unroll
            for (int j = 0; j < 4; j++) {
                int k = k0 + g * 128 + tc4 + j;
                float ws = wsq[k];
#pragma unroll
                for (int i = 0; i < 8; i++) {
                    float s = ws - 2.0f * acc[i][g * 4 + j];
                    if (s < rmin[i]) { rmin[i] = s; ridx[i] = k; }
                }
            }
    }
#pragma unroll
    for (int off = 1; off < 32; off <<= 1) {
#pragma unroll
        for (int i = 0; i < 8; i++) {
            float ov = __shfl_xor(rmin[i], off);
            int oi = __shfl_xor(ridx[i], off);
            if (ov < rmin[i] || (ov == rmin[i] && oi < ridx[i])) { rmin[i] = ov; ridx[i] = oi; }
        }
    }
    if (tc == 0) {
#pragma unroll
        for (int i = 0; i < 8; i++) {
            int n = n0 + tr8 + i;
            ws_idx[n] = ridx[i];
            out_idx_f[n] = (float)ridx[i];
        }
    }
}

// ---------------- gather z_q + loss SSE ----------------
__global__ void gather_loss_kernel(const float* __restrict__ x, const float* __restrict__ W,
                                   const int* __restrict__ ws_idx,
                                   float* __restrict__ out_zq, float* __restrict__ loss_acc) {
    __shared__ float red[256];
    const size_t P4 = (size_t)N_ROWS * D_DIM / 4;
    size_t tid = (size_t)blockIdx.x * blockDim.x + threadIdx.x;
    size_t stride = (size_t)gridDim.x * blockDim.x;
    float acc = 0.0f;
    for (size_t p4 = tid; p4 < P4; p4 += stride) {
        int n = (int)(p4 >> 6);
        int j = (int)((p4 & 63) << 2);
        int k = ws_idx[n];
        float4 wv = *(const float4*)(W + (size_t)k * D_DIM + j);
        float4 xv = *(const float4*)(x + p4 * 4);
        float dx = wv.x - xv.x, dy = wv.y - xv.y, dz = wv.z - xv.z, dw = wv.w - xv.w;
        acc += dx * dx + dy * dy + dz * dz + dw * dw;
        *(float4*)(out_zq + p4 * 4) = wv;
    }
    red[threadIdx.x] = acc;
    __syncthreads();
    for (int s = 128; s > 0; s >>= 1) {
        if ((int)threadIdx.x < s) red[threadIdx.x] += red[threadIdx.x + s];
        __syncthreads();
    }
    if (threadIdx.x == 0) atomicAdd(loss_acc, red[0]);
}

__global__ void finalize_kernel(const float* __restrict__ loss_acc, float* __restrict__ out_loss) {
    out_loss[0] = 1.25f * loss_acc[0] * (1.0f / 8388608.0f);
}

extern "C" void kernel_launch(void* const* d_in, const int* in_sizes, int n_in,
                              void* d_out, int out_size, void* d_ws, size_t ws_size,
                              hipStream_t stream) {
    const float* x = (const float*)d_in[0];
    const float* W = (const float*)d_in[1];

    float* out      = (float*)d_out;
    float* out_zq   = out;                         // 8388608 f32
    float* out_idx  = out + 8388608;               // 32768 f32
    float* out_loss = out + 8388608 + 32768;       // 1 f32

    // workspace layout
    float* loss_acc = (float*)d_ws;                              // @0
    int*   scount   = (int*)((char*)d_ws + 8);                   // @8
    float* wsq      = (float*)((char*)d_ws + 1024);              // 4 KB
    int*   ws_idx   = (int*)((char*)d_ws + 8192);                // 128 KB
    int*   slist    = (int*)((char*)d_ws + 139264);              // 128 KB
    unsigned short* Wh = (unsigned short*)((char*)d_ws + 270336);   // 512 KB
    unsigned short* Wl = (unsigned short*)((char*)d_ws + 794624);   // 512 KB
    float* pws      = (float*)((char*)d_ws + 1318912);           // 3 MB
    const size_t NEEDED = 4464640;

    if (ws_size >= NEEDED) {
        // Zh/Zl bf16 live in the out_zq region (2 x 16.78 MB); gather overwrites later.
        unsigned short* Zh = (unsigned short*)out_zq;
        unsigned short* Zl = Zh + (size_t)N_ROWS * D_DIM;

        prep_kernel<<<256, 256, 0, stream>>>(W, wsq, Wh, Wl, loss_acc, scount);
        convz_kernel<<<2048, 256, 0, stream>>>(x, Zh, Zl);
        mm_argmin_kernel<<<2048, 256, 0, stream>>>(Zh, Zl, Wh, Wl, wsq, pws);
        combine_kernel<<<128, 256, 0, stream>>>(pws, out_idx, ws_idx, scount, slist);
        rescore_kernel<<<256, 256, 0, stream>>>(x, W, wsq, scount, slist, out_idx, ws_idx);
    } else {
        prep_kernel<<<256, 256, 0, stream>>>(W, wsq, Wh, Wl, loss_acc, scount);
        argmin_f32_kernel<<<N_ROWS / FROWS, 256, 0, stream>>>(x, W, wsq, out_idx, ws_idx);
    }

    gather_loss_kernel<<<2048, 256, 0, stream>>>(x, W, ws_idx, out_zq, loss_acc);
    finalize_kernel<<<1, 1, 0, stream>>>(loss_acc, out_loss);
}

// Round 9
// 190.274 us; speedup vs baseline: 1.1433x; 1.1433x over previous
//
#include <hip/hip_runtime.h>

// VQ-VAE codebook quantization — R9: R3's 24-chunk all-LDS structure + all proven fixes
//   (fragment-major conflict-free LDS, XCD-chunked swizzle, triple-buffer + counted
//    vmcnt(4) + single barrier/chunk, setprio).
//   x: [32, 256, 32, 32] f32 -> z: [N=32768, D=256]; W: [1024, 256] f32
//   idx[n] = argmin_k (|w_k|^2 - 2 z_n.w_k)
//   bf16 3-term split (pass-major: hh over d, then lh, then hl), error <= ~2e-4
//   << MARGIN; rows with (second - best) <= MARGIN exactly rescored in fp32.
// Outputs flat f32: z_q (8388608), idx-as-float (32768), loss (1)

#define N_ROWS 32768
#define K_CODES 1024
#define D_DIM 256
#define MARGIN 0.015625f

using f32x4  = __attribute__((ext_vector_type(4))) float;
using bf16x8 = __attribute__((ext_vector_type(8))) short;

__device__ __forceinline__ unsigned int rne_bf16(float f) {
    unsigned int u = __float_as_uint(f);
    return (u + 0x7FFFu + ((u >> 16) & 1u)) >> 16;   // round-to-nearest-even bf16 bits
}

// ---------------- fused: wsq (exact fp32) + W->bf16 hi/lo + acc zeroing ----------------
__global__ void prep_kernel(const float* __restrict__ W, float* __restrict__ wsq,
                            unsigned short* __restrict__ Wh, unsigned short* __restrict__ Wl,
                            float* __restrict__ loss_acc, int* __restrict__ scount) {
    int p = blockIdx.x * 256 + threadIdx.x;    // 65536 float4s
    if (p == 0) { *loss_acc = 0.0f; *scount = 0; }
    float4 v = *(const float4*)(W + (size_t)p * 4);
    unsigned int h0 = rne_bf16(v.x), h1 = rne_bf16(v.y), h2 = rne_bf16(v.z), h3 = rne_bf16(v.w);
    float f0 = __uint_as_float(h0 << 16), f1 = __uint_as_float(h1 << 16);
    float f2 = __uint_as_float(h2 << 16), f3 = __uint_as_float(h3 << 16);
    unsigned int l0 = rne_bf16(v.x - f0), l1 = rne_bf16(v.y - f1);
    unsigned int l2 = rne_bf16(v.z - f2), l3 = rne_bf16(v.w - f3);
    *(uint2*)(Wh + (size_t)p * 4) = make_uint2(h0 | (h1 << 16), h2 | (h3 << 16));
    *(uint2*)(Wl + (size_t)p * 4) = make_uint2(l0 | (l1 << 16), l2 | (l3 << 16));
    if (p < K_CODES) {
        const float4* w4 = (const float4*)(W + (size_t)p * D_DIM);
        float s = 0.0f;
#pragma unroll 8
        for (int i = 0; i < D_DIM / 4; i++) {
            float4 q = w4[i];
            s += q.x * q.x + q.y * q.y + q.z * q.z + q.w * q.w;
        }
        wsq[p] = s;
    }
}

// ---------------- x -> Zh/Zl bf16 [n][d] (transpose via LDS) ----------------
__global__ void convz_kernel(const float* __restrict__ x, unsigned short* __restrict__ Zh,
                             unsigned short* __restrict__ Zl) {
    __shared__ float tile[64][65];
    const int bid = blockIdx.x;            // 2048 = 32 b * 4 dblk * 16 hwblk
    const int b = bid >> 6, dblk = (bid >> 4) & 3, hwblk = bid & 15;
    const int t = threadIdx.x;
    const float* xb = x + ((size_t)(b * 256 + dblk * 64)) * 1024 + hwblk * 64;
#pragma unroll
    for (int i = 0; i < 4; i++) {
        int dl = i * 16 + (t >> 4);
        int hl = (t & 15) * 4;
        float4 v = *(const float4*)(xb + (size_t)dl * 1024 + hl);
        tile[dl][hl] = v.x; tile[dl][hl + 1] = v.y; tile[dl][hl + 2] = v.z; tile[dl][hl + 3] = v.w;
    }
    __syncthreads();
    const int n0 = b * 1024 + hwblk * 64, d0 = dblk * 64;
#pragma unroll
    for (int j = 0; j < 2; j++) {
        int r = j * 32 + (t >> 3);
        int dc = (t & 7) * 8;
        unsigned int hi[8], lo[8];
#pragma unroll
        for (int q = 0; q < 8; q++) {
            float f = tile[dc + q][r];
            hi[q] = rne_bf16(f);
            lo[q] = rne_bf16(f - __uint_as_float(hi[q] << 16));
        }
        uint4 hp = make_uint4(hi[0] | (hi[1] << 16), hi[2] | (hi[3] << 16),
                              hi[4] | (hi[5] << 16), hi[6] | (hi[7] << 16));
        uint4 lp = make_uint4(lo[0] | (lo[1] << 16), lo[2] | (lo[3] << 16),
                              lo[4] | (lo[5] << 16), lo[6] | (lo[7] << 16));
        *(uint4*)(Zh + (size_t)(n0 + r) * 256 + d0 + dc) = hp;
        *(uint4*)(Zl + (size_t)(n0 + r) * 256 + d0 + dc) = lp;
    }
}

// ---------------- MFMA distance GEMM + best/second argmin ----------------
// Block: 128 codes x 128 zrows; 4 waves (wm,wn); per-wave 64x64 = 4x4 frags 16x16x32.
// 24 chunks of 32 dims (pass-major: 8 hh, 8 lh, 8 hl). BOTH operands staged
// fragment-major in LDS via global_load_lds (conflict-free ds_read_b128).
// Triple-buffered: stage(ch+1) at top of iter ch (targets buf last read at ch-2,
// finished by all waves before barrier(ch-1) -> race-free), counted vmcnt(4)
// leaves next chunk's 4 gll in flight, ONE barrier per chunk.
__launch_bounds__(256, 3)
__global__ void mm_argmin_kernel(const unsigned short* __restrict__ Zh,
                                 const unsigned short* __restrict__ Zl,
                                 const unsigned short* __restrict__ Wh,
                                 const unsigned short* __restrict__ Wl,
                                 const float* __restrict__ wsq, float* __restrict__ pws) {
    __shared__ unsigned short LS[3][2][4096];   // [buf][A/B][8 frags x 512 ushort] = 48 KB

    const int t = threadIdx.x;
    const int w = t >> 6, lane = t & 63;
    const int wm = w & 1, wn = w >> 1;
    // XCD-chunked bijective decode (2048 blocks, 8 XCDs round-robin by blockIdx&7)
    const int g  = blockIdx.x & 7;          // XCD
    const int s  = blockIdx.x >> 3;         // per-XCD sequence 0..255
    const int cb = s & 7;                   // 8 consecutive same-XCD slots share nb
    const int nb = g * 32 + (s >> 3);
    const int c0 = cb * 128, n0 = nb * 128;

    const int lrow = lane & 15;             // fragment row within 16
    const int lk   = (lane >> 4) << 3;      // fragment k-offset (ushorts)
    const int f0 = w * 2;                   // frags staged by this wave (A and B)

    f32x4 acc[4][4];
#pragma unroll
    for (int i = 0; i < 4; i++)
#pragma unroll
        for (int j = 0; j < 4; j++) acc[i][j] = (f32x4){0.f, 0.f, 0.f, 0.f};

    // stage chunk: A-frag f = codes c0+f*16, B-frag f = zrows n0+f*16; dims d0..d0+32
#define STAGE(buf_, pA_, pB_, d0_)                                                        \
    _Pragma("unroll")                                                                     \
    for (int j_ = 0; j_ < 2; j_++) {                                                      \
        const int f_ = f0 + j_;                                                           \
        const size_t ao_ = ((size_t)(c0 + f_ * 16 + lrow) << 8) + (d0_) + lk;             \
        __builtin_amdgcn_global_load_lds(                                                 \
            (const __attribute__((address_space(1))) void*)((pA_) + ao_),                 \
            (__attribute__((address_space(3))) void*)&LS[buf_][0][f_ * 512], 16, 0, 0);   \
        const size_t bo_ = ((size_t)(n0 + f_ * 16 + lrow) << 8) + (d0_) + lk;             \
        __builtin_amdgcn_global_load_lds(                                                 \
            (const __attribute__((address_space(1))) void*)((pB_) + bo_),                 \
            (__attribute__((address_space(3))) void*)&LS[buf_][1][f_ * 512], 16, 0, 0);   \
    }

    STAGE(0, Wh, Zh, 0);

#pragma unroll 1
    for (int ch = 0; ch < 24; ++ch) {
        const int buf = ch % 3;             // wave-uniform (SALU)
        if (ch < 23) {
            const int cn = ch + 1;
            const int pn = cn >> 3;         // next pass: 0 hh, 1 lh, 2 hl
            const unsigned short* pA = (pn == 1) ? Wl : Wh;
            const unsigned short* pB = (pn == 2) ? Zl : Zh;
            STAGE(cn % 3, pA, pB, (cn & 7) * 32);
            __builtin_amdgcn_sched_barrier(0);   // gll issue order pinned before the count
            // outstanding: [gll(ch) x4 oldest][gll(ch+1) x4] -> drain only gll(ch)
            asm volatile("s_waitcnt vmcnt(4)" ::: "memory");
        } else {
            asm volatile("s_waitcnt vmcnt(0)" ::: "memory");
        }
        __builtin_amdgcn_s_barrier();       // all waves' gll(ch) landed in LS[buf]
        __builtin_amdgcn_sched_barrier(0);  // ds_reads must not hoist above

        bf16x8 af[4], bf[4];
#pragma unroll
        for (int mf = 0; mf < 4; mf++)
            af[mf] = *(const bf16x8*)&LS[buf][0][(wm * 4 + mf) * 512 + (lane << 3)];
#pragma unroll
        for (int nf = 0; nf < 4; nf++)
            bf[nf] = *(const bf16x8*)&LS[buf][1][(wn * 4 + nf) * 512 + (lane << 3)];

        __builtin_amdgcn_s_setprio(1);
#pragma unroll
        for (int mf = 0; mf < 4; mf++)
#pragma unroll
            for (int nf = 0; nf < 4; nf++)
                acc[mf][nf] = __builtin_amdgcn_mfma_f32_16x16x32_bf16(af[mf], bf[nf], acc[mf][nf], 0, 0, 0);
        __builtin_amdgcn_s_setprio(0);
    }
#undef STAGE

    // ---- epilogue: scores + best/second argmin
    // lane's codes: c0 + wm*64 + mf*16 + (lane>>4)*4 + r ; zrow col = lane&15 (per nf)
    float ws16[16];
#pragma unroll
    for (int mf = 0; mf < 4; mf++)
#pragma unroll
        for (int r = 0; r < 4; r++)
            ws16[mf * 4 + r] = wsq[c0 + wm * 64 + mf * 16 + ((lane >> 4) << 2) + r];

    float b1[4], b2[4]; int i1[4];
#pragma unroll
    for (int nf = 0; nf < 4; nf++) {
        b1[nf] = 1e30f; b2[nf] = 1e30f; i1[nf] = 0;
#pragma unroll
        for (int mf = 0; mf < 4; mf++)
#pragma unroll
            for (int r = 0; r < 4; r++) {
                float s2 = ws16[mf * 4 + r] - 2.0f * acc[mf][nf][r];
                int code = c0 + wm * 64 + mf * 16 + ((lane >> 4) << 2) + r;
                if (s2 < b1[nf]) { b2[nf] = b1[nf]; b1[nf] = s2; i1[nf] = code; }
                else if (s2 < b2[nf]) b2[nf] = s2;
            }
    }
    // merge across the 4 k-lane-groups holding the same zrow (lane&15)
#pragma unroll
    for (int off = 16; off <= 32; off <<= 1) {
#pragma unroll
        for (int nf = 0; nf < 4; nf++) {
            float ob1 = __shfl_xor(b1[nf], off);
            float ob2 = __shfl_xor(b2[nf], off);
            int   oi1 = __shfl_xor(i1[nf], off);
            float nb2 = fminf(fminf(b2[nf], ob2), fmaxf(b1[nf], ob1));
            if (ob1 < b1[nf] || (ob1 == b1[nf] && oi1 < i1[nf])) { b1[nf] = ob1; i1[nf] = oi1; }
            b2[nf] = nb2;
        }
    }
    // red[2][128][3] overlays LS (K-loop done). Barrier before overwrite.
    float* red = (float*)&LS[0][0][0];
    __syncthreads();
    if ((lane >> 4) == 0) {
#pragma unroll
        for (int nf = 0; nf < 4; nf++) {
            int zr = wn * 64 + nf * 16 + (lane & 15);
            red[(wm * 128 + zr) * 3 + 0] = b1[nf];
            red[(wm * 128 + zr) * 3 + 1] = __int_as_float(i1[nf]);
            red[(wm * 128 + zr) * 3 + 2] = b2[nf];
        }
    }
    __syncthreads();
    if (t < 128) {
        float a1 = red[t * 3 + 0], ai = red[t * 3 + 1], a2 = red[t * 3 + 2];
        float c1 = red[(128 + t) * 3 + 0], ci = red[(128 + t) * 3 + 1], c2 = red[(128 + t) * 3 + 2];
        float m2 = fminf(fminf(a2, c2), fmaxf(a1, c1));
        float m1 = a1, mi = ai;
        if (c1 < a1) { m1 = c1; mi = ci; }   // tie keeps wm0 (lower codes)
        float* dst = pws + ((size_t)(n0 + t) * 8 + cb) * 3;
        dst[0] = m1; dst[1] = mi; dst[2] = m2;
    }
}

// ---------------- combine 8 code-block partials; flag suspects ----------------
__global__ void combine_kernel(const float* __restrict__ pws, float* __restrict__ out_idx_f,
                               int* __restrict__ ws_idx, int* __restrict__ scount,
                               int* __restrict__ slist) {
    int n = blockIdx.x * 256 + threadIdx.x;
    float b1 = 1e30f, bi = 0.f, b2 = 1e30f;
    const float* e = pws + (size_t)n * 24;
#pragma unroll
    for (int cbk = 0; cbk < 8; cbk++) {
        float e1 = e[cbk * 3 + 0], ei = e[cbk * 3 + 1], e2 = e[cbk * 3 + 2];
        float m2 = fminf(fminf(b2, e2), fmaxf(b1, e1));
        if (e1 < b1) { b1 = e1; bi = ei; }   // ties keep earlier cb (lower codes)
        b2 = m2;
    }
    int idx = __float_as_int(bi);
    ws_idx[n] = idx;
    out_idx_f[n] = (float)idx;
    if (b2 - b1 <= MARGIN) {
        int pos = atomicAdd(scount, 1);
        slist[pos] = n;
    }
}

// ---------------- exact fp32 rescore of suspect rows ----------------
__global__ void rescore_kernel(const float* __restrict__ x, const float* __restrict__ W,
                               const float* __restrict__ wsq, const int* __restrict__ scount,
                               const int* __restrict__ slist, float* __restrict__ out_idx_f,
                               int* __restrict__ ws_idx) {
    __shared__ float zrow[256];
    __shared__ float rv[256];
    __shared__ int   ri[256];
    const int cnt = *scount;
    for (int s = blockIdx.x; s < cnt; s += gridDim.x) {
        const int n = slist[s];
        const int b = n >> 10, hw = n & 1023;
        __syncthreads();
        zrow[threadIdx.x] = x[(((size_t)(b * 256 + threadIdx.x)) << 10) + hw];
        __syncthreads();
        float best = 1e30f; int bidx = 0;
        for (int j = 0; j < 4; j++) {
            const int k = threadIdx.x + j * 256;    // ascending per thread
            const float4* wr = (const float4*)(W + (size_t)k * 256);
            float dot = 0.f;
#pragma unroll 16
            for (int q = 0; q < 64; q++) {
                float4 wv = wr[q];
                float4 zv = *(const float4*)&zrow[q * 4];
                dot = fmaf(wv.x, zv.x, dot); dot = fmaf(wv.y, zv.y, dot);
                dot = fmaf(wv.z, zv.z, dot); dot = fmaf(wv.w, zv.w, dot);
            }
            float sc = wsq[k] - 2.f * dot;
            if (sc < best) { best = sc; bidx = k; }
        }
        rv[threadIdx.x] = best; ri[threadIdx.x] = bidx;
        __syncthreads();
        for (int st = 128; st > 0; st >>= 1) {
            if ((int)threadIdx.x < st) {
                float ov = rv[threadIdx.x + st]; int oi = ri[threadIdx.x + st];
                if (ov < rv[threadIdx.x] || (ov == rv[threadIdx.x] && oi < ri[threadIdx.x])) {
                    rv[threadIdx.x] = ov; ri[threadIdx.x] = oi;
                }
            }
            __syncthreads();
        }
        if (threadIdx.x == 0) { ws_idx[n] = ri[0]; out_idx_f[n] = (float)ri[0]; }
    }
}

// ---------------- fallback fp32 argmin (proven R1 kernel, used if ws too small) ----------------
#define FROWS 64
#define FKT 256
#define FDT 32
#define FKTP 260

__launch_bounds__(256, 3)
__global__ void argmin_f32_kernel(const float* __restrict__ x, const float* __restrict__ W,
                                  const float* __restrict__ wsq,
                                  float* __restrict__ out_idx_f, int* __restrict__ ws_idx) {
    __shared__ float zT[FDT][FROWS];
    __shared__ float wT[FDT][FKTP];
    const int t = threadIdx.x;
    const int lane = t & 63;
    const int wv = t >> 6;
    const int tc = t & 31;
    const int tr = t >> 5;
    const int tr8 = tr * 8, tc4 = tc * 4;
    const int n0 = blockIdx.x * FROWS;
    const int b = n0 >> 10;
    const int hw0 = n0 & 1023;
    const size_t xbase = (size_t)b * D_DIM * 1024;
    float rmin[8]; int ridx[8];
#pragma unroll
    for (int i = 0; i < 8; i++) { rmin[i] = 1e30f; ridx[i] = 0; }
#pragma unroll 1
    for (int k0 = 0; k0 < K_CODES; k0 += FKT) {
        float acc[8][8] = {{0.f}};
#pragma unroll 1
        for (int d0 = 0; d0 < D_DIM; d0 += FDT) {
#pragma unroll
            for (int i = 0; i < 2; i++) {
                int dl0 = wv * 8 + i * 4;
                const float* src = x + xbase + ((size_t)(d0 + dl0 + (lane >> 4)) << 10)
                                 + hw0 + ((lane & 15) << 2);
                __builtin_amdgcn_global_load_lds(
                    (const __attribute__((address_space(1))) void*)src,
                    (__attribute__((address_space(3))) void*)&zT[dl0][0], 16, 0, 0);
            }
#pragma unroll
            for (int i = 0; i < 8; i++) {
                int e = t + i * 256;
                int kk = e >> 3, dg = e & 7;
                float4 v = *(const float4*)(W + (size_t)(k0 + kk) * D_DIM + d0 + dg * 4);
                wT[dg * 4 + 0][kk] = v.x; wT[dg * 4 + 1][kk] = v.y;
                wT[dg * 4 + 2][kk] = v.z; wT[dg * 4 + 3][kk] = v.w;
            }
            __syncthreads();
#pragma unroll 4
            for (int d = 0; d < FDT; d++) {
                float zr[8], wc[8];
                *(float4*)&zr[0] = *(const float4*)&zT[d][tr8];
                *(float4*)&zr[4] = *(const float4*)&zT[d][tr8 + 4];
                *(float4*)&wc[0] = *(const float4*)&wT[d][tc4];
                *(float4*)&wc[4] = *(const float4*)&wT[d][tc4 + 128];
#pragma unroll
                for (int i = 0; i < 8; i++)
#pragma unroll
                    for (int j = 0; j < 8; j++)
                        acc[i][j] = fmaf(zr[i], wc[j], acc[i][j]);
            }
            __syncthreads();
        }
#pragma unroll
        for (int g = 0; g < 2; g++)
#pragma unroll
            for (int j = 0; j < 4; j++) {
                int k = k0 + g * 128 + tc4 + j;
                float ws = wsq[k];
#pragma unroll
                for (int i = 0; i < 8; i++) {
                    float s = ws - 2.0f * acc[i][g * 4 + j];
                    if (s < rmin[i]) { rmin[i] = s; ridx[i] = k; }
                }
            }
    }
#pragma unroll
    for (int off = 1; off < 32; off <<= 1) {
#pragma unroll
        for (int i = 0; i < 8; i++) {
            float ov = __shfl_xor(rmin[i], off);
            int oi = __shfl_xor(ridx[i], off);
            if (ov < rmin[i] || (ov == rmin[i] && oi < ridx[i])) { rmin[i] = ov; ridx[i] = oi; }
        }
    }
    if (tc == 0) {
#pragma unroll
        for (int i = 0; i < 8; i++) {
            int n = n0 + tr8 + i;
            ws_idx[n] = ridx[i];
            out_idx_f[n] = (float)ridx[i];
        }
    }
}

// ---------------- gather z_q + loss SSE ----------------
__global__ void gather_loss_kernel(const float* __restrict__ x, const float* __restrict__ W,
                                   const int* __restrict__ ws_idx,
                                   float* __restrict__ out_zq, float* __restrict__ loss_acc) {
    __shared__ float red[256];
    const size_t P4 = (size_t)N_ROWS * D_DIM / 4;
    size_t tid = (size_t)blockIdx.x * blockDim.x + threadIdx.x;
    size_t stride = (size_t)gridDim.x * blockDim.x;
    float acc = 0.0f;
    for (size_t p4 = tid; p4 < P4; p4 += stride) {
        int n = (int)(p4 >> 6);
        int j = (int)((p4 & 63) << 2);
        int k = ws_idx[n];
        float4 wv = *(const float4*)(W + (size_t)k * D_DIM + j);
        float4 xv = *(const float4*)(x + p4 * 4);
        float dx = wv.x - xv.x, dy = wv.y - xv.y, dz = wv.z - xv.z, dw = wv.w - xv.w;
        acc += dx * dx + dy * dy + dz * dz + dw * dw;
        *(float4*)(out_zq + p4 * 4) = wv;
    }
    red[threadIdx.x] = acc;
    __syncthreads();
    for (int s = 128; s > 0; s >>= 1) {
        if ((int)threadIdx.x < s) red[threadIdx.x] += red[threadIdx.x + s];
        __syncthreads();
    }
    if (threadIdx.x == 0) atomicAdd(loss_acc, red[0]);
}

__global__ void finalize_kernel(const float* __restrict__ loss_acc, float* __restrict__ out_loss) {
    out_loss[0] = 1.25f * loss_acc[0] * (1.0f / 8388608.0f);
}

extern "C" void kernel_launch(void* const* d_in, const int* in_sizes, int n_in,
                              void* d_out, int out_size, void* d_ws, size_t ws_size,
                              hipStream_t stream) {
    const float* x = (const float*)d_in[0];
    const float* W = (const float*)d_in[1];

    float* out      = (float*)d_out;
    float* out_zq   = out;                         // 8388608 f32
    float* out_idx  = out + 8388608;               // 32768 f32
    float* out_loss = out + 8388608 + 32768;       // 1 f32

    // workspace layout
    float* loss_acc = (float*)d_ws;                              // @0
    int*   scount   = (int*)((char*)d_ws + 8);                   // @8
    float* wsq      = (float*)((char*)d_ws + 1024);              // 4 KB
    int*   ws_idx   = (int*)((char*)d_ws + 8192);                // 128 KB
    int*   slist    = (int*)((char*)d_ws + 139264);              // 128 KB
    unsigned short* Wh = (unsigned short*)((char*)d_ws + 270336);   // 512 KB
    unsigned short* Wl = (unsigned short*)((char*)d_ws + 794624);   // 512 KB
    float* pws      = (float*)((char*)d_ws + 1318912);           // 3 MB
    const size_t NEEDED = 4464640;

    if (ws_size >= NEEDED) {
        // Zh/Zl bf16 live in the out_zq region (2 x 16.78 MB); gather overwrites later.
        unsigned short* Zh = (unsigned short*)out_zq;
        unsigned short* Zl = Zh + (size_t)N_ROWS * D_DIM;

        prep_kernel<<<256, 256, 0, stream>>>(W, wsq, Wh, Wl, loss_acc, scount);
        convz_kernel<<<2048, 256, 0, stream>>>(x, Zh, Zl);
        mm_argmin_kernel<<<2048, 256, 0, stream>>>(Zh, Zl, Wh, Wl, wsq, pws);
        combine_kernel<<<128, 256, 0, stream>>>(pws, out_idx, ws_idx, scount, slist);
        rescore_kernel<<<256, 256, 0, stream>>>(x, W, wsq, scount, slist, out_idx, ws_idx);
    } else {
        prep_kernel<<<256, 256, 0, stream>>>(W, wsq, Wh, Wl, loss_acc, scount);
        argmin_f32_kernel<<<N_ROWS / FROWS, 256, 0, stream>>>(x, W, wsq, out_idx, ws_idx);
    }

    gather_loss_kernel<<<2048, 256, 0, stream>>>(x, W, ws_idx, out_zq, loss_acc);
    finalize_kernel<<<1, 1, 0, stream>>>(loss_acc, out_loss);
}

// Round 10
// 154.832 us; speedup vs baseline: 1.4050x; 1.2289x over previous
//
#include <hip/hip_runtime.h>

// VQ-VAE codebook quantization — R10: pre-fragmented operands, barrier-free MFMA GEMM.
//   x: [32, 256, 32, 32] f32 -> z: [N=32768, D=256]; W: [1024, 256] f32
//   idx[n] = argmin_k (|w_k|^2 - 2 z_n.w_k)
//   bf16 3-term split (pass-major: hh, lh, hl over d), error <= ~2e-4 << MARGIN;
//   rows with (second - best) <= MARGIN exactly rescored in fp32.
// Key idea: convz/prep write Z and W in FRAGMENT-MAJOR global layout — each
// 16-row x 32-dim MFMA fragment is 1 KB contiguous in exact lane order
// (ushort idx = ((tile*8 + ch)*8 + frag)*512 + lane*8). The GEMM K-loop then
// reads operands with fully-coalesced b128 loads from L2: no LDS, no barriers,
// waves free-run and self-stagger (kills the barrier-convoy that pinned R5-R9
// at ~103 us regardless of scheduling).
// Outputs flat f32: z_q (8388608), idx-as-float (32768), loss (1)

#define N_ROWS 32768
#define K_CODES 1024
#define D_DIM 256
#define MARGIN 0.015625f

using f32x4  = __attribute__((ext_vector_type(4))) float;
using bf16x8 = __attribute__((ext_vector_type(8))) short;

__device__ __forceinline__ unsigned int rne_bf16(float f) {
    unsigned int u = __float_as_uint(f);
    return (u + 0x7FFFu + ((u >> 16) & 1u)) >> 16;   // round-to-nearest-even bf16 bits
}

// ---------------- fused: wsq + W -> fragment-major bf16 hi/lo ----------------
// Wf layout (ushorts): ((cb*8 + ch)*8 + fr)*512 + lane*8  (+4 for upper half-lane)
//   cb = k>>7, fr = (k>>4)&7, lrow = k&15; ch = d>>5, lane = lrow + ((d>>3)&3)*16
__global__ void prep_kernel(const float* __restrict__ W, float* __restrict__ wsq,
                            unsigned short* __restrict__ Wfh, unsigned short* __restrict__ Wfl,
                            float* __restrict__ loss_acc, int* __restrict__ scount) {
    int p = blockIdx.x * 256 + threadIdx.x;    // 65536 float4s
    if (p == 0) { *loss_acc = 0.0f; *scount = 0; }
    const int k  = p >> 6;
    const int fq = p & 63;
    const int dg = fq * 4;                     // first of 4 dims
    float4 v = *(const float4*)(W + (size_t)p * 4);
    unsigned int h0 = rne_bf16(v.x), h1 = rne_bf16(v.y), h2 = rne_bf16(v.z), h3 = rne_bf16(v.w);
    float f0 = __uint_as_float(h0 << 16), f1 = __uint_as_float(h1 << 16);
    float f2 = __uint_as_float(h2 << 16), f3 = __uint_as_float(h3 << 16);
    unsigned int l0 = rne_bf16(v.x - f0), l1 = rne_bf16(v.y - f1);
    unsigned int l2 = rne_bf16(v.z - f2), l3 = rne_bf16(v.w - f3);
    const int cb = k >> 7, fr = (k >> 4) & 7, lrow = k & 15;
    const int ch = dg >> 5;
    const int lane = lrow + ((dg >> 3) & 3) * 16;
    const size_t idx = ((size_t)((cb * 8 + ch) * 8 + fr)) * 512 + lane * 8 + ((dg >> 2) & 1) * 4;
    *(uint2*)(Wfh + idx) = make_uint2(h0 | (h1 << 16), h2 | (h3 << 16));
    *(uint2*)(Wfl + idx) = make_uint2(l0 | (l1 << 16), l2 | (l3 << 16));
    if (p < K_CODES) {
        const float4* w4 = (const float4*)(W + (size_t)p * D_DIM);
        float s = 0.0f;
#pragma unroll 8
        for (int i = 0; i < D_DIM / 4; i++) {
            float4 q = w4[i];
            s += q.x * q.x + q.y * q.y + q.z * q.z + q.w * q.w;
        }
        wsq[p] = s;
    }
}

// ---------------- x -> Zfh/Zfl fragment-major bf16 (transpose via LDS) ----------------
// Zf layout (ushorts): ((nb*8 + ch)*8 + fr)*512 + lane*8
//   nb = n>>7, fr = (n>>4)&7, lrow = n&15; ch = d>>5, lane = lrow + ((d>>3)&3)*16
__global__ void convz_kernel(const float* __restrict__ x, unsigned short* __restrict__ Zfh,
                             unsigned short* __restrict__ Zfl) {
    __shared__ float tile[64][65];
    const int bid = blockIdx.x;            // 2048 = 32 b * 4 dblk * 16 hwblk
    const int b = bid >> 6, dblk = (bid >> 4) & 3, hwblk = bid & 15;
    const int t = threadIdx.x;
    const float* xb = x + ((size_t)(b * 256 + dblk * 64)) * 1024 + hwblk * 64;
#pragma unroll
    for (int i = 0; i < 4; i++) {
        int dl = i * 16 + (t >> 4);
        int hl = (t & 15) * 4;
        float4 v = *(const float4*)(xb + (size_t)dl * 1024 + hl);
        tile[dl][hl] = v.x; tile[dl][hl + 1] = v.y; tile[dl][hl + 2] = v.z; tile[dl][hl + 3] = v.w;
    }
    __syncthreads();
    const int n0 = b * 1024 + hwblk * 64, d0 = dblk * 64;
#pragma unroll
    for (int j = 0; j < 2; j++) {
        int r = j * 32 + (t >> 3);
        int dc = (t & 7) * 8;              // 8 dims within the 64-dim tile
        unsigned int hi[8], lo[8];
#pragma unroll
        for (int q = 0; q < 8; q++) {
            float f = tile[dc + q][r];
            hi[q] = rne_bf16(f);
            lo[q] = rne_bf16(f - __uint_as_float(hi[q] << 16));
        }
        uint4 hp = make_uint4(hi[0] | (hi[1] << 16), hi[2] | (hi[3] << 16),
                              hi[4] | (hi[5] << 16), hi[6] | (hi[7] << 16));
        uint4 lp = make_uint4(lo[0] | (lo[1] << 16), lo[2] | (lo[3] << 16),
                              lo[4] | (lo[5] << 16), lo[6] | (lo[7] << 16));
        const int n  = n0 + r;
        const int dg = d0 + dc;
        const int nb = n >> 7, fr = (n >> 4) & 7, lrow = n & 15;
        const int ch = dg >> 5;
        const int lane = lrow + ((dg >> 3) & 3) * 16;
        const size_t idx = ((size_t)((nb * 8 + ch) * 8 + fr)) * 512 + lane * 8;
        *(uint4*)(Zfh + idx) = hp;
        *(uint4*)(Zfl + idx) = lp;
    }
}

// ---------------- MFMA distance GEMM + best/second argmin (barrier-free) ----------------
// Block: 128 codes x 128 zrows; 4 waves (wm,wn); per-wave 64x64 = 4x4 frags 16x16x32.
// 24 unrolled steps (pass-major: 8 hh, 8 lh, 8 hl), per step: 8 fully-coalesced
// 1-KB b128 loads (4 A frags + 4 B frags, L2-hot) + 16 independent MFMAs.
// 1-deep register double-buffer; NO LDS, NO barriers — waves self-stagger.
__launch_bounds__(256, 3)
__global__ void mm_argmin_kernel(const unsigned short* __restrict__ Zfh,
                                 const unsigned short* __restrict__ Zfl,
                                 const unsigned short* __restrict__ Wfh,
                                 const unsigned short* __restrict__ Wfl,
                                 const float* __restrict__ wsq, float* __restrict__ pws) {
    __shared__ float red[2][128][3];        // 3 KB (epilogue only)

    const int t = threadIdx.x;
    const int w = t >> 6, lane = t & 63;
    const int wm = w & 1, wn = w >> 1;
    // XCD-chunked bijective decode (2048 blocks, 8 XCDs round-robin by blockIdx&7)
    const int g  = blockIdx.x & 7;          // XCD
    const int s  = blockIdx.x >> 3;         // per-XCD sequence 0..255
    const int cb = s & 7;                   // 8 consecutive same-XCD slots share nb
    const int nb = g * 32 + (s >> 3);
    const int c0 = cb * 128, n0 = nb * 128;

    const int l8 = lane << 3;               // ushort offset of this lane in a frag block
    const size_t aB = (size_t)cb * 32768 + (wm * 4) * 512 + l8;   // + ch*4096 + mf*512
    const size_t bB = (size_t)nb * 32768 + (wn * 4) * 512 + l8;

    f32x4 acc[4][4];
#pragma unroll
    for (int i = 0; i < 4; i++)
#pragma unroll
        for (int j = 0; j < 4; j++) acc[i][j] = (f32x4){0.f, 0.f, 0.f, 0.f};

    bf16x8 Af[2][4], Bf[2][4];              // 64 VGPR operand double-buffer

#define LOADF(dst_, psrc_, base_, ch_)                                        \
    _Pragma("unroll")                                                         \
    for (int f_ = 0; f_ < 4; f_++)                                            \
        dst_[f_] = *(const bf16x8*)((psrc_) + (base_) + (ch_) * 4096 + f_ * 512);

    LOADF(Af[0], Wfh, aB, 0);
    LOADF(Bf[0], Zfh, bB, 0);

#pragma unroll
    for (int pc = 0; pc < 24; ++pc) {       // full unroll -> all indices static
        const int cs = pc & 1;
        if (pc < 23) {
            const int nx = pc + 1;
            const int pn = nx >> 3;         // next pass: 0 hh, 1 lh, 2 hl
            const int cn = nx & 7;          // next d-chunk
            const unsigned short* pa = (pn == 1) ? Wfl : Wfh;
            const unsigned short* pb = (pn == 2) ? Zfl : Zfh;
            LOADF(Af[cs ^ 1], pa, aB, cn);
            LOADF(Bf[cs ^ 1], pb, bB, cn);
        }
        __builtin_amdgcn_s_setprio(1);
#pragma unroll
        for (int mf = 0; mf < 4; mf++)
#pragma unroll
            for (int nf = 0; nf < 4; nf++)
                acc[mf][nf] = __builtin_amdgcn_mfma_f32_16x16x32_bf16(Af[cs][mf], Bf[cs][nf], acc[mf][nf], 0, 0, 0);
        __builtin_amdgcn_s_setprio(0);
    }
#undef LOADF

    // ---- epilogue: scores + best/second argmin
    // lane's codes: c0 + wm*64 + mf*16 + (lane>>4)*4 + r ; zrow col = lane&15 (per nf)
    float ws16[16];
#pragma unroll
    for (int mf = 0; mf < 4; mf++)
#pragma unroll
        for (int r = 0; r < 4; r++)
            ws16[mf * 4 + r] = wsq[c0 + wm * 64 + mf * 16 + ((lane >> 4) << 2) + r];

    float b1[4], b2[4]; int i1[4];
#pragma unroll
    for (int nf = 0; nf < 4; nf++) {
        b1[nf] = 1e30f; b2[nf] = 1e30f; i1[nf] = 0;
#pragma unroll
        for (int mf = 0; mf < 4; mf++)
#pragma unroll
            for (int r = 0; r < 4; r++) {
                float s2 = ws16[mf * 4 + r] - 2.0f * acc[mf][nf][r];
                int code = c0 + wm * 64 + mf * 16 + ((lane >> 4) << 2) + r;
                if (s2 < b1[nf]) { b2[nf] = b1[nf]; b1[nf] = s2; i1[nf] = code; }
                else if (s2 < b2[nf]) b2[nf] = s2;
            }
    }
    // merge across the 4 k-lane-groups holding the same zrow (lane&15)
#pragma unroll
    for (int off = 16; off <= 32; off <<= 1) {
#pragma unroll
        for (int nf = 0; nf < 4; nf++) {
            float ob1 = __shfl_xor(b1[nf], off);
            float ob2 = __shfl_xor(b2[nf], off);
            int   oi1 = __shfl_xor(i1[nf], off);
            float nb2 = fminf(fminf(b2[nf], ob2), fmaxf(b1[nf], ob1));
            if (ob1 < b1[nf] || (ob1 == b1[nf] && oi1 < i1[nf])) { b1[nf] = ob1; i1[nf] = oi1; }
            b2[nf] = nb2;
        }
    }
    if ((lane >> 4) == 0) {
#pragma unroll
        for (int nf = 0; nf < 4; nf++) {
            int zr = wn * 64 + nf * 16 + (lane & 15);
            red[wm][zr][0] = b1[nf];
            red[wm][zr][1] = __int_as_float(i1[nf]);
            red[wm][zr][2] = b2[nf];
        }
    }
    __syncthreads();
    if (t < 128) {
        float a1 = red[0][t][0], ai = red[0][t][1], a2 = red[0][t][2];
        float c1 = red[1][t][0], ci = red[1][t][1], c2 = red[1][t][2];
        float m2 = fminf(fminf(a2, c2), fmaxf(a1, c1));
        float m1 = a1, mi = ai;
        if (c1 < a1) { m1 = c1; mi = ci; }   // tie keeps wm0 (lower codes)
        float* dst = pws + ((size_t)(n0 + t) * 8 + cb) * 3;
        dst[0] = m1; dst[1] = mi; dst[2] = m2;
    }
}

// ---------------- combine 8 code-block partials; flag suspects ----------------
__global__ void combine_kernel(const float* __restrict__ pws, float* __restrict__ out_idx_f,
                               int* __restrict__ ws_idx, int* __restrict__ scount,
                               int* __restrict__ slist) {
    int n = blockIdx.x * 256 + threadIdx.x;
    float b1 = 1e30f, bi = 0.f, b2 = 1e30f;
    const float* e = pws + (size_t)n * 24;
#pragma unroll
    for (int cbk = 0; cbk < 8; cbk++) {
        float e1 = e[cbk * 3 + 0], ei = e[cbk * 3 + 1], e2 = e[cbk * 3 + 2];
        float m2 = fminf(fminf(b2, e2), fmaxf(b1, e1));
        if (e1 < b1) { b1 = e1; bi = ei; }   // ties keep earlier cb (lower codes)
        b2 = m2;
    }
    int idx = __float_as_int(bi);
    ws_idx[n] = idx;
    out_idx_f[n] = (float)idx;
    if (b2 - b1 <= MARGIN) {
        int pos = atomicAdd(scount, 1);
        slist[pos] = n;
    }
}

// ---------------- exact fp32 rescore of suspect rows ----------------
__global__ void rescore_kernel(const float* __restrict__ x, const float* __restrict__ W,
                               const float* __restrict__ wsq, const int* __restrict__ scount,
                               const int* __restrict__ slist, float* __restrict__ out_idx_f,
                               int* __restrict__ ws_idx) {
    __shared__ float zrow[256];
    __shared__ float rv[256];
    __shared__ int   ri[256];
    const int cnt = *scount;
    for (int s = blockIdx.x; s < cnt; s += gridDim.x) {
        const int n = slist[s];
        const int b = n >> 10, hw = n & 1023;
        __syncthreads();
        zrow[threadIdx.x] = x[(((size_t)(b * 256 + threadIdx.x)) << 10) + hw];
        __syncthreads();
        float best = 1e30f; int bidx = 0;
        for (int j = 0; j < 4; j++) {
            const int k = threadIdx.x + j * 256;    // ascending per thread
            const float4* wr = (const float4*)(W + (size_t)k * 256);
            float dot = 0.f;
#pragma unroll 16
            for (int q = 0; q < 64; q++) {
                float4 wv = wr[q];
                float4 zv = *(const float4*)&zrow[q * 4];
                dot = fmaf(wv.x, zv.x, dot); dot = fmaf(wv.y, zv.y, dot);
                dot = fmaf(wv.z, zv.z, dot); dot = fmaf(wv.w, zv.w, dot);
            }
            float sc = wsq[k] - 2.f * dot;
            if (sc < best) { best = sc; bidx = k; }
        }
        rv[threadIdx.x] = best; ri[threadIdx.x] = bidx;
        __syncthreads();
        for (int st = 128; st > 0; st >>= 1) {
            if ((int)threadIdx.x < st) {
                float ov = rv[threadIdx.x + st]; int oi = ri[threadIdx.x + st];
                if (ov < rv[threadIdx.x] || (ov == rv[threadIdx.x] && oi < ri[threadIdx.x])) {
                    rv[threadIdx.x] = ov; ri[threadIdx.x] = oi;
                }
            }
            __syncthreads();
        }
        if (threadIdx.x == 0) { ws_idx[n] = ri[0]; out_idx_f[n] = (float)ri[0]; }
    }
}

// ---------------- fallback path helpers (ws too small) ----------------
__global__ void wsq_only_kernel(const float* __restrict__ W, float* __restrict__ wsq,
                                float* __restrict__ loss_acc) {
    int k = blockIdx.x * blockDim.x + threadIdx.x;
    if (k == 0) *loss_acc = 0.0f;
    if (k < K_CODES) {
        const float4* w4 = (const float4*)(W + (size_t)k * D_DIM);
        float s = 0.0f;
#pragma unroll 8
        for (int i = 0; i < D_DIM / 4; i++) {
            float4 v = w4[i];
            s += v.x * v.x + v.y * v.y + v.z * v.z + v.w * v.w;
        }
        wsq[k] = s;
    }
}

#define FROWS 64
#define FKT 256
#define FDT 32
#define FKTP 260

__launch_bounds__(256, 3)
__global__ void argmin_f32_kernel(const float* __restrict__ x, const float* __restrict__ W,
                                  const float* __restrict__ wsq,
                                  float* __restrict__ out_idx_f, int* __restrict__ ws_idx) {
    __shared__ float zT[FDT][FROWS];
    __shared__ float wT[FDT][FKTP];
    const int t = threadIdx.x;
    const int lane = t & 63;
    const int wv = t >> 6;
    const int tc = t & 31;
    const int tr = t >> 5;
    const int tr8 = tr * 8, tc4 = tc * 4;
    const int n0 = blockIdx.x * FROWS;
    const int b = n0 >> 10;
    const int hw0 = n0 & 1023;
    const size_t xbase = (size_t)b * D_DIM * 1024;
    float rmin[8]; int ridx[8];
#pragma unroll
    for (int i = 0; i < 8; i++) { rmin[i] = 1e30f; ridx[i] = 0; }
#pragma unroll 1
    for (int k0 = 0; k0 < K_CODES; k0 += FKT) {
        float acc[8][8] = {{0.f}};
#pragma unroll 1
        for (int d0 = 0; d0 < D_DIM; d0 += FDT) {
#pragma unroll
            for (int i = 0; i < 2; i++) {
                int dl0 = wv * 8 + i * 4;
                const float* src = x + xbase + ((size_t)(d0 + dl0 + (lane >> 4)) << 10)
                                 + hw0 + ((lane & 15) << 2);
                __builtin_amdgcn_global_load_lds(
                    (const __attribute__((address_space(1))) void*)src,
                    (__attribute__((address_space(3))) void*)&zT[dl0][0], 16, 0, 0);
            }
#pragma unroll
            for (int i = 0; i < 8; i++) {
                int e = t + i * 256;
                int kk = e >> 3, dg = e & 7;
                float4 v = *(const float4*)(W + (size_t)(k0 + kk) * D_DIM + d0 + dg * 4);
                wT[dg * 4 + 0][kk] = v.x; wT[dg * 4 + 1][kk] = v.y;
                wT[dg * 4 + 2][kk] = v.z; wT[dg * 4 + 3][kk] = v.w;
            }
            __syncthreads();
#pragma unroll 4
            for (int d = 0; d < FDT; d++) {
                float zr[8], wc[8];
                *(float4*)&zr[0] = *(const float4*)&zT[d][tr8];
                *(float4*)&zr[4] = *(const float4*)&zT[d][tr8 + 4];
                *(float4*)&wc[0] = *(const float4*)&wT[d][tc4];
                *(float4*)&wc[4] = *(const float4*)&wT[d][tc4 + 128];
#pragma unroll
                for (int i = 0; i < 8; i++)
#pragma unroll
                    for (int j = 0; j < 8; j++)
                        acc[i][j] = fmaf(zr[i], wc[j], acc[i][j]);
            }
            __syncthreads();
        }
#pragma unroll
        for (int g = 0; g < 2; g++)
#pragma unroll
            for (int j = 0; j < 4; j++) {
                int k = k0 + g * 128 + tc4 + j;
                float ws = wsq[k];
#pragma unroll
                for (int i = 0; i < 8; i++) {
                    float s = ws - 2.0f * acc[i][g * 4 + j];
                    if (s < rmin[i]) { rmin[i] = s; ridx[i] = k; }
                }
            }
    }
#pragma unroll
    for (int off = 1; off < 32; off <<= 1) {
#pragma unroll
        for (int i = 0; i < 8; i++) {
            float ov = __shfl_xor(rmin[i], off);
            int oi = __shfl_xor(ridx[i], off);
            if (ov < rmin[i] || (ov == rmin[i] && oi < ridx[i])) { rmin[i] = ov; ridx[i] = oi; }
        }
    }
    if (tc == 0) {
#pragma unroll
        for (int i = 0; i < 8; i++) {
            int n = n0 + tr8 + i;
            ws_idx[n] = ridx[i];
            out_idx_f[n] = (float)ridx[i];
        }
    }
}

// ---------------- gather z_q + loss SSE ----------------
__global__ void gather_loss_kernel(const float* __restrict__ x, const float* __restrict__ W,
                                   const int* __restrict__ ws_idx,
                                   float* __restrict__ out_zq, float* __restrict__ loss_acc) {
    __shared__ float red[256];
    const size_t P4 = (size_t)N_ROWS * D_DIM / 4;
    size_t tid = (size_t)blockIdx.x * blockDim.x + threadIdx.x;
    size_t stride = (size_t)gridDim.x * blockDim.x;
    float acc = 0.0f;
    for (size_t p4 = tid; p4 < P4; p4 += stride) {
        int n = (int)(p4 >> 6);
        int j = (int)((p4 & 63) << 2);
        int k = ws_idx[n];
        float4 wv = *(const float4*)(W + (size_t)k * D_DIM + j);
        float4 xv = *(const float4*)(x + p4 * 4);
        float dx = wv.x - xv.x, dy = wv.y - xv.y, dz = wv.z - xv.z, dw = wv.w - xv.w;
        acc += dx * dx + dy * dy + dz * dz + dw * dw;
        *(float4*)(out_zq + p4 * 4) = wv;
    }
    red[threadIdx.x] = acc;
    __syncthreads();
    for (int s = 128; s > 0; s >>= 1) {
        if ((int)threadIdx.x < s) red[threadIdx.x] += red[threadIdx.x + s];
        __syncthreads();
    }
    if (threadIdx.x == 0) atomicAdd(loss_acc, red[0]);
}

__global__ void finalize_kernel(const float* __restrict__ loss_acc, float* __restrict__ out_loss) {
    out_loss[0] = 1.25f * loss_acc[0] * (1.0f / 8388608.0f);
}

extern "C" void kernel_launch(void* const* d_in, const int* in_sizes, int n_in,
                              void* d_out, int out_size, void* d_ws, size_t ws_size,
                              hipStream_t stream) {
    const float* x = (const float*)d_in[0];
    const float* W = (const float*)d_in[1];

    float* out      = (float*)d_out;
    float* out_zq   = out;                         // 8388608 f32
    float* out_idx  = out + 8388608;               // 32768 f32
    float* out_loss = out + 8388608 + 32768;       // 1 f32

    // workspace layout
    float* loss_acc = (float*)d_ws;                              // @0
    int*   scount   = (int*)((char*)d_ws + 8);                   // @8
    float* wsq      = (float*)((char*)d_ws + 1024);              // 4 KB
    int*   ws_idx   = (int*)((char*)d_ws + 8192);                // 128 KB
    int*   slist    = (int*)((char*)d_ws + 139264);              // 128 KB
    unsigned short* Wfh = (unsigned short*)((char*)d_ws + 270336);  // 512 KB
    unsigned short* Wfl = (unsigned short*)((char*)d_ws + 794624);  // 512 KB
    float* pws      = (float*)((char*)d_ws + 1318912);           // 3 MB
    const size_t NEEDED = 4464640;

    if (ws_size >= NEEDED) {
        // Zfh/Zfl fragment-major bf16 live in the out_zq region (2 x 16.78 MB);
        // gather overwrites later.
        unsigned short* Zfh = (unsigned short*)out_zq;
        unsigned short* Zfl = Zfh + (size_t)N_ROWS * D_DIM;

        prep_kernel<<<256, 256, 0, stream>>>(W, wsq, Wfh, Wfl, loss_acc, scount);
        convz_kernel<<<2048, 256, 0, stream>>>(x, Zfh, Zfl);
        mm_argmin_kernel<<<2048, 256, 0, stream>>>(Zfh, Zfl, Wfh, Wfl, wsq, pws);
        combine_kernel<<<128, 256, 0, stream>>>(pws, out_idx, ws_idx, scount, slist);
        rescore_kernel<<<256, 256, 0, stream>>>(x, W, wsq, scount, slist, out_idx, ws_idx);
    } else {
        wsq_only_kernel<<<4, 256, 0, stream>>>(W, wsq, loss_acc);
        argmin_f32_kernel<<<N_ROWS / FROWS, 256, 0, stream>>>(x, W, wsq, out_idx, ws_idx);
    }

    gather_loss_kernel<<<2048, 256, 0, stream>>>(x, W, ws_idx, out_zq, loss_acc);
    finalize_kernel<<<1, 1, 0, stream>>>(loss_acc, out_loss);
}

// Round 11
// 141.988 us; speedup vs baseline: 1.5321x; 1.0905x over previous
//
#include <hip/hip_runtime.h>

// VQ-VAE codebook quantization — R11: chunk-major operand loads (1.5x less L1 traffic),
//   coalesced fragment-major convz writes, tightened rescore margin.
//   x: [32, 256, 32, 32] f32 -> z: [N=32768, D=256]; W: [1024, 256] f32
//   idx[n] = argmin_k (|w_k|^2 - 2 z_n.w_k)
//   bf16 3-term split (per-chunk: hh, lh, hl), |error| <= ~3e-4 << MARGIN;
//   rows with (second - best) <= MARGIN exactly rescored in fp32.
// Fragment-major global layout: each 16-row x 32-dim MFMA fragment is 1 KB
// contiguous in exact lane order (ushort idx = ((tile*8 + ch)*8 + fr)*512 + lane*8).
// GEMM K-loop: fully-coalesced b128 loads from L2, no LDS, no barriers.
// Outputs flat f32: z_q (8388608), idx-as-float (32768), loss (1)

#define N_ROWS 32768
#define K_CODES 1024
#define D_DIM 256
#define MARGIN 0.00390625f

using f32x4  = __attribute__((ext_vector_type(4))) float;
using bf16x8 = __attribute__((ext_vector_type(8))) short;

__device__ __forceinline__ unsigned int rne_bf16(float f) {
    unsigned int u = __float_as_uint(f);
    return (u + 0x7FFFu + ((u >> 16) & 1u)) >> 16;   // round-to-nearest-even bf16 bits
}

// ---------------- fused: wsq + W -> fragment-major bf16 hi/lo ----------------
// Wf layout (ushorts): ((cb*8 + ch)*8 + fr)*512 + lane*8  (+4 for upper half-lane)
//   cb = k>>7, fr = (k>>4)&7, lrow = k&15; ch = d>>5, lane = lrow + ((d>>3)&3)*16
__global__ void prep_kernel(const float* __restrict__ W, float* __restrict__ wsq,
                            unsigned short* __restrict__ Wfh, unsigned short* __restrict__ Wfl,
                            float* __restrict__ loss_acc, int* __restrict__ scount) {
    int p = blockIdx.x * 256 + threadIdx.x;    // 65536 float4s
    if (p == 0) { *loss_acc = 0.0f; *scount = 0; }
    const int k  = p >> 6;
    const int fq = p & 63;
    const int dg = fq * 4;                     // first of 4 dims
    float4 v = *(const float4*)(W + (size_t)p * 4);
    unsigned int h0 = rne_bf16(v.x), h1 = rne_bf16(v.y), h2 = rne_bf16(v.z), h3 = rne_bf16(v.w);
    float f0 = __uint_as_float(h0 << 16), f1 = __uint_as_float(h1 << 16);
    float f2 = __uint_as_float(h2 << 16), f3 = __uint_as_float(h3 << 16);
    unsigned int l0 = rne_bf16(v.x - f0), l1 = rne_bf16(v.y - f1);
    unsigned int l2 = rne_bf16(v.z - f2), l3 = rne_bf16(v.w - f3);
    const int cb = k >> 7, fr = (k >> 4) & 7, lrow = k & 15;
    const int ch = dg >> 5;
    const int lane = lrow + ((dg >> 3) & 3) * 16;
    const size_t idx = ((size_t)((cb * 8 + ch) * 8 + fr)) * 512 + lane * 8 + ((dg >> 2) & 1) * 4;
    *(uint2*)(Wfh + idx) = make_uint2(h0 | (h1 << 16), h2 | (h3 << 16));
    *(uint2*)(Wfl + idx) = make_uint2(l0 | (l1 << 16), l2 | (l3 << 16));
    if (p < K_CODES) {
        const float4* w4 = (const float4*)(W + (size_t)p * D_DIM);
        float s = 0.0f;
#pragma unroll 8
        for (int i = 0; i < D_DIM / 4; i++) {
            float4 q = w4[i];
            s += q.x * q.x + q.y * q.y + q.z * q.z + q.w * q.w;
        }
        wsq[p] = s;
    }
}

// ---------------- x -> Zfh/Zfl fragment-major bf16 (LDS transpose, coalesced writes) ----
// Per block: 64 n x 64 d tile -> 8 fragment blocks (4 fr x 2 ch) x (h,l).
// Each wave emits whole 1-KB fragment blocks: lane L writes uint4 at idx + L*8
// -> perfectly coalesced stores (fixes R10's 16B-scattered write amplification).
__global__ void convz_kernel(const float* __restrict__ x, unsigned short* __restrict__ Zfh,
                             unsigned short* __restrict__ Zfl) {
    __shared__ float tile[64][65];
    const int bid = blockIdx.x;            // 2048 = 32 b * 4 dblk * 16 hwblk
    const int b = bid >> 6, dblk = (bid >> 4) & 3, hwblk = bid & 15;
    const int t = threadIdx.x;
    const float* xb = x + ((size_t)(b * 256 + dblk * 64)) * 1024 + hwblk * 64;
#pragma unroll
    for (int i = 0; i < 4; i++) {
        int dl = i * 16 + (t >> 4);
        int hl = (t & 15) * 4;
        float4 v = *(const float4*)(xb + (size_t)dl * 1024 + hl);
        tile[dl][hl] = v.x; tile[dl][hl + 1] = v.y; tile[dl][hl + 2] = v.z; tile[dl][hl + 3] = v.w;
    }
    __syncthreads();
    const int w = t >> 6, L = t & 63;
    const int n0  = b * 1024 + hwblk * 64;
    const int nb  = n0 >> 7;
    const int frb = (n0 >> 4) & 7;         // 0 or 4 (n0 multiple of 64)
#pragma unroll
    for (int j = 0; j < 2; j++) {
        const int fb  = w * 2 + j;         // 0..7
        const int chl = fb >> 2, frl = fb & 3;
        const int dgl = chl * 32 + (L >> 4) * 8;   // local dim base for this lane
        const int r   = frl * 16 + (L & 15);       // local row
        unsigned int hi[8], lo[8];
#pragma unroll
        for (int q = 0; q < 8; q++) {
            float f = tile[dgl + q][r];
            hi[q] = rne_bf16(f);
            lo[q] = rne_bf16(f - __uint_as_float(hi[q] << 16));
        }
        uint4 hp = make_uint4(hi[0] | (hi[1] << 16), hi[2] | (hi[3] << 16),
                              hi[4] | (hi[5] << 16), hi[6] | (hi[7] << 16));
        uint4 lp = make_uint4(lo[0] | (lo[1] << 16), lo[2] | (lo[3] << 16),
                              lo[4] | (lo[5] << 16), lo[6] | (lo[7] << 16));
        const int chg = dblk * 2 + chl;
        const int frg = frb + frl;
        const size_t idx = ((size_t)((nb * 8 + chg) * 8 + frg)) * 512 + L * 8;
        *(uint4*)(Zfh + idx) = hp;
        *(uint4*)(Zfl + idx) = lp;
    }
}

// ---------------- MFMA distance GEMM + best/second argmin (barrier-free) ----------------
// Block: 128 codes x 128 zrows; 4 waves (wm,wn); per-wave 64x64 = 4x4 frags 16x16x32.
// 8 chunks of 32 dims, CHUNK-MAJOR: per chunk load {Ah,Al,Bh,Bl} once (16 coalesced
// 1-KB b128 loads) then 48 MFMAs (hh, lh, hl — each 16 independent). 1.5x less
// L1/L2 traffic than pass-major and 3x the MFMA-per-load-batch for latency cover.
// NO LDS, NO barriers — waves self-stagger; compiler pipelines across unrolled chunks.
__launch_bounds__(256, 3)
__global__ void mm_argmin_kernel(const unsigned short* __restrict__ Zfh,
                                 const unsigned short* __restrict__ Zfl,
                                 const unsigned short* __restrict__ Wfh,
                                 const unsigned short* __restrict__ Wfl,
                                 const float* __restrict__ wsq, float* __restrict__ pws) {
    __shared__ float red[2][128][3];        // 3 KB (epilogue only)

    const int t = threadIdx.x;
    const int w = t >> 6, lane = t & 63;
    const int wm = w & 1, wn = w >> 1;
    // XCD-chunked bijective decode (2048 blocks, 8 XCDs round-robin by blockIdx&7)
    const int g  = blockIdx.x & 7;          // XCD
    const int s  = blockIdx.x >> 3;         // per-XCD sequence 0..255
    const int cb = s & 7;                   // 8 consecutive same-XCD slots share nb
    const int nb = g * 32 + (s >> 3);
    const int c0 = cb * 128, n0 = nb * 128;

    const int l8 = lane << 3;               // ushort offset of this lane in a frag block
    const size_t aB = (size_t)cb * 32768 + (wm * 4) * 512 + l8;   // + ch*4096 + mf*512
    const size_t bB = (size_t)nb * 32768 + (wn * 4) * 512 + l8;

    f32x4 acc[4][4];
#pragma unroll
    for (int i = 0; i < 4; i++)
#pragma unroll
        for (int j = 0; j < 4; j++) acc[i][j] = (f32x4){0.f, 0.f, 0.f, 0.f};

#define LOADF(dst_, psrc_, base_, ch_)                                        \
    _Pragma("unroll")                                                         \
    for (int f_ = 0; f_ < 4; f_++)                                            \
        dst_[f_] = *(const bf16x8*)((psrc_) + (base_) + (ch_) * 4096 + f_ * 512);

#pragma unroll
    for (int ch = 0; ch < 8; ++ch) {        // full unroll -> all indices static
        bf16x8 Ah[4], Al[4], Bh[4], Bl[4];  // 64 VGPR, single set
        LOADF(Ah, Wfh, aB, ch);
        LOADF(Bh, Zfh, bB, ch);
        LOADF(Al, Wfl, aB, ch);
        LOADF(Bl, Zfl, bB, ch);
        __builtin_amdgcn_s_setprio(1);
        // hh — 16 independent MFMAs
#pragma unroll
        for (int mf = 0; mf < 4; mf++)
#pragma unroll
            for (int nf = 0; nf < 4; nf++)
                acc[mf][nf] = __builtin_amdgcn_mfma_f32_16x16x32_bf16(Ah[mf], Bh[nf], acc[mf][nf], 0, 0, 0);
        // lh
#pragma unroll
        for (int mf = 0; mf < 4; mf++)
#pragma unroll
            for (int nf = 0; nf < 4; nf++)
                acc[mf][nf] = __builtin_amdgcn_mfma_f32_16x16x32_bf16(Al[mf], Bh[nf], acc[mf][nf], 0, 0, 0);
        // hl
#pragma unroll
        for (int mf = 0; mf < 4; mf++)
#pragma unroll
            for (int nf = 0; nf < 4; nf++)
                acc[mf][nf] = __builtin_amdgcn_mfma_f32_16x16x32_bf16(Ah[mf], Bl[nf], acc[mf][nf], 0, 0, 0);
        __builtin_amdgcn_s_setprio(0);
    }
#undef LOADF

    // ---- epilogue: scores + best/second argmin
    // lane's codes: c0 + wm*64 + mf*16 + (lane>>4)*4 + r ; zrow col = lane&15 (per nf)
    float ws16[16];
#pragma unroll
    for (int mf = 0; mf < 4; mf++)
#pragma unroll
        for (int r = 0; r < 4; r++)
            ws16[mf * 4 + r] = wsq[c0 + wm * 64 + mf * 16 + ((lane >> 4) << 2) + r];

    float b1[4], b2[4]; int i1[4];
#pragma unroll
    for (int nf = 0; nf < 4; nf++) {
        b1[nf] = 1e30f; b2[nf] = 1e30f; i1[nf] = 0;
#pragma unroll
        for (int mf = 0; mf < 4; mf++)
#pragma unroll
            for (int r = 0; r < 4; r++) {
                float s2 = ws16[mf * 4 + r] - 2.0f * acc[mf][nf][r];
                int code = c0 + wm * 64 + mf * 16 + ((lane >> 4) << 2) + r;
                if (s2 < b1[nf]) { b2[nf] = b1[nf]; b1[nf] = s2; i1[nf] = code; }
                else if (s2 < b2[nf]) b2[nf] = s2;
            }
    }
    // merge across the 4 k-lane-groups holding the same zrow (lane&15)
#pragma unroll
    for (int off = 16; off <= 32; off <<= 1) {
#pragma unroll
        for (int nf = 0; nf < 4; nf++) {
            float ob1 = __shfl_xor(b1[nf], off);
            float ob2 = __shfl_xor(b2[nf], off);
            int   oi1 = __shfl_xor(i1[nf], off);
            float nb2 = fminf(fminf(b2[nf], ob2), fmaxf(b1[nf], ob1));
            if (ob1 < b1[nf] || (ob1 == b1[nf] && oi1 < i1[nf])) { b1[nf] = ob1; i1[nf] = oi1; }
            b2[nf] = nb2;
        }
    }
    if ((lane >> 4) == 0) {
#pragma unroll
        for (int nf = 0; nf < 4; nf++) {
            int zr = wn * 64 + nf * 16 + (lane & 15);
            red[wm][zr][0] = b1[nf];
            red[wm][zr][1] = __int_as_float(i1[nf]);
            red[wm][zr][2] = b2[nf];
        }
    }
    __syncthreads();
    if (t < 128) {
        float a1 = red[0][t][0], ai = red[0][t][1], a2 = red[0][t][2];
        float c1 = red[1][t][0], ci = red[1][t][1], c2 = red[1][t][2];
        float m2 = fminf(fminf(a2, c2), fmaxf(a1, c1));
        float m1 = a1, mi = ai;
        if (c1 < a1) { m1 = c1; mi = ci; }   // tie keeps wm0 (lower codes)
        float* dst = pws + ((size_t)(n0 + t) * 8 + cb) * 3;
        dst[0] = m1; dst[1] = mi; dst[2] = m2;
    }
}

// ---------------- combine 8 code-block partials; flag suspects ----------------
__global__ void combine_kernel(const float* __restrict__ pws, float* __restrict__ out_idx_f,
                               int* __restrict__ ws_idx, int* __restrict__ scount,
                               int* __restrict__ slist) {
    int n = blockIdx.x * 256 + threadIdx.x;
    float b1 = 1e30f, bi = 0.f, b2 = 1e30f;
    const float* e = pws + (size_t)n * 24;
#pragma unroll
    for (int cbk = 0; cbk < 8; cbk++) {
        float e1 = e[cbk * 3 + 0], ei = e[cbk * 3 + 1], e2 = e[cbk * 3 + 2];
        float m2 = fminf(fminf(b2, e2), fmaxf(b1, e1));
        if (e1 < b1) { b1 = e1; bi = ei; }   // ties keep earlier cb (lower codes)
        b2 = m2;
    }
    int idx = __float_as_int(bi);
    ws_idx[n] = idx;
    out_idx_f[n] = (float)idx;
    if (b2 - b1 <= MARGIN) {
        int pos = atomicAdd(scount, 1);
        slist[pos] = n;
    }
}

// ---------------- exact fp32 rescore of suspect rows ----------------
__global__ void rescore_kernel(const float* __restrict__ x, const float* __restrict__ W,
                               const float* __restrict__ wsq, const int* __restrict__ scount,
                               const int* __restrict__ slist, float* __restrict__ out_idx_f,
                               int* __restrict__ ws_idx) {
    __shared__ float zrow[256];
    __shared__ float rv[256];
    __shared__ int   ri[256];
    const int cnt = *scount;
    for (int s = blockIdx.x; s < cnt; s += gridDim.x) {
        const int n = slist[s];
        const int b = n >> 10, hw = n & 1023;
        __syncthreads();
        zrow[threadIdx.x] = x[(((size_t)(b * 256 + threadIdx.x)) << 10) + hw];
        __syncthreads();
        float best = 1e30f; int bidx = 0;
        for (int j = 0; j < 4; j++) {
            const int k = threadIdx.x + j * 256;    // ascending per thread
            const float4* wr = (const float4*)(W + (size_t)k * 256);
            float dot = 0.f;
#pragma unroll 16
            for (int q = 0; q < 64; q++) {
                float4 wv = wr[q];
                float4 zv = *(const float4*)&zrow[q * 4];
                dot = fmaf(wv.x, zv.x, dot); dot = fmaf(wv.y, zv.y, dot);
                dot = fmaf(wv.z, zv.z, dot); dot = fmaf(wv.w, zv.w, dot);
            }
            float sc = wsq[k] - 2.f * dot;
            if (sc < best) { best = sc; bidx = k; }
        }
        rv[threadIdx.x] = best; ri[threadIdx.x] = bidx;
        __syncthreads();
        for (int st = 128; st > 0; st >>= 1) {
            if ((int)threadIdx.x < st) {
                float ov = rv[threadIdx.x + st]; int oi = ri[threadIdx.x + st];
                if (ov < rv[threadIdx.x] || (ov == rv[threadIdx.x] && oi < ri[threadIdx.x])) {
                    rv[threadIdx.x] = ov; ri[threadIdx.x] = oi;
                }
            }
            __syncthreads();
        }
        if (threadIdx.x == 0) { ws_idx[n] = ri[0]; out_idx_f[n] = (float)ri[0]; }
    }
}

// ---------------- fallback path helpers (ws too small) ----------------
__global__ void wsq_only_kernel(const float* __restrict__ W, float* __restrict__ wsq,
                                float* __restrict__ loss_acc) {
    int k = blockIdx.x * blockDim.x + threadIdx.x;
    if (k == 0) *loss_acc = 0.0f;
    if (k < K_CODES) {
        const float4* w4 = (const float4*)(W + (size_t)k * D_DIM);
        float s = 0.0f;
#pragma unroll 8
        for (int i = 0; i < D_DIM / 4; i++) {
            float4 v = w4[i];
            s += v.x * v.x + v.y * v.y + v.z * v.z + v.w * v.w;
        }
        wsq[k] = s;
    }
}

#define FROWS 64
#define FKT 256
#define FDT 32
#define FKTP 260

__launch_bounds__(256, 3)
__global__ void argmin_f32_kernel(const float* __restrict__ x, const float* __restrict__ W,
                                  const float* __restrict__ wsq,
                                  float* __restrict__ out_idx_f, int* __restrict__ ws_idx) {
    __shared__ float zT[FDT][FROWS];
    __shared__ float wT[FDT][FKTP];
    const int t = threadIdx.x;
    const int lane = t & 63;
    const int wv = t >> 6;
    const int tc = t & 31;
    const int tr = t >> 5;
    const int tr8 = tr * 8, tc4 = tc * 4;
    const int n0 = blockIdx.x * FROWS;
    const int b = n0 >> 10;
    const int hw0 = n0 & 1023;
    const size_t xbase = (size_t)b * D_DIM * 1024;
    float rmin[8]; int ridx[8];
#pragma unroll
    for (int i = 0; i < 8; i++) { rmin[i] = 1e30f; ridx[i] = 0; }
#pragma unroll 1
    for (int k0 = 0; k0 < K_CODES; k0 += FKT) {
        float acc[8][8] = {{0.f}};
#pragma unroll 1
        for (int d0 = 0; d0 < D_DIM; d0 += FDT) {
#pragma unroll
            for (int i = 0; i < 2; i++) {
                int dl0 = wv * 8 + i * 4;
                const float* src = x + xbase + ((size_t)(d0 + dl0 + (lane >> 4)) << 10)
                                 + hw0 + ((lane & 15) << 2);
                __builtin_amdgcn_global_load_lds(
                    (const __attribute__((address_space(1))) void*)src,
                    (__attribute__((address_space(3))) void*)&zT[dl0][0], 16, 0, 0);
            }
#pragma unroll
            for (int i = 0; i < 8; i++) {
                int e = t + i * 256;
                int kk = e >> 3, dg = e & 7;
                float4 v = *(const float4*)(W + (size_t)(k0 + kk) * D_DIM + d0 + dg * 4);
                wT[dg * 4 + 0][kk] = v.x; wT[dg * 4 + 1][kk] = v.y;
                wT[dg * 4 + 2][kk] = v.z; wT[dg * 4 + 3][kk] = v.w;
            }
            __syncthreads();
#pragma unroll 4
            for (int d = 0; d < FDT; d++) {
                float zr[8], wc[8];
                *(float4*)&zr[0] = *(const float4*)&zT[d][tr8];
                *(float4*)&zr[4] = *(const float4*)&zT[d][tr8 + 4];
                *(float4*)&wc[0] = *(const float4*)&wT[d][tc4];
                *(float4*)&wc[4] = *(const float4*)&wT[d][tc4 + 128];
#pragma unroll
                for (int i = 0; i < 8; i++)
#pragma unroll
                    for (int j = 0; j < 8; j++)
                        acc[i][j] = fmaf(zr[i], wc[j], acc[i][j]);
            }
            __syncthreads();
        }
#pragma unroll
        for (int g = 0; g < 2; g++)
#pragma unroll
            for (int j = 0; j < 4; j++) {
                int k = k0 + g * 128 + tc4 + j;
                float ws = wsq[k];
#pragma unroll
                for (int i = 0; i < 8; i++) {
                    float s = ws - 2.0f * acc[i][g * 4 + j];
                    if (s < rmin[i]) { rmin[i] = s; ridx[i] = k; }
                }
            }
    }
#pragma unroll
    for (int off = 1; off < 32; off <<= 1) {
#pragma unroll
        for (int i = 0; i < 8; i++) {
            float ov = __shfl_xor(rmin[i], off);
            int oi = __shfl_xor(ridx[i], off);
            if (ov < rmin[i] || (ov == rmin[i] && oi < ridx[i])) { rmin[i] = ov; ridx[i] = oi; }
        }
    }
    if (tc == 0) {
#pragma unroll
        for (int i = 0; i < 8; i++) {
            int n = n0 + tr8 + i;
            ws_idx[n] = ridx[i];
            out_idx_f[n] = (float)ridx[i];
        }
    }
}

// ---------------- gather z_q + loss SSE ----------------
__global__ void gather_loss_kernel(const float* __restrict__ x, const float* __restrict__ W,
                                   const int* __restrict__ ws_idx,
                                   float* __restrict__ out_zq, float* __restrict__ loss_acc) {
    __shared__ float red[256];
    const size_t P4 = (size_t)N_ROWS * D_DIM / 4;
    size_t tid = (size_t)blockIdx.x * blockDim.x + threadIdx.x;
    size_t stride = (size_t)gridDim.x * blockDim.x;
    float acc = 0.0f;
    for (size_t p4 = tid; p4 < P4; p4 += stride) {
        int n = (int)(p4 >> 6);
        int j = (int)((p4 & 63) << 2);
        int k = ws_idx[n];
        float4 wv = *(const float4*)(W + (size_t)k * D_DIM + j);
        float4 xv = *(const float4*)(x + p4 * 4);
        float dx = wv.x - xv.x, dy = wv.y - xv.y, dz = wv.z - xv.z, dw = wv.w - xv.w;
        acc += dx * dx + dy * dy + dz * dz + dw * dw;
        *(float4*)(out_zq + p4 * 4) = wv;
    }
    red[threadIdx.x] = acc;
    __syncthreads();
    for (int s = 128; s > 0; s >>= 1) {
        if ((int)threadIdx.x < s) red[threadIdx.x] += red[threadIdx.x + s];
        __syncthreads();
    }
    if (threadIdx.x == 0) atomicAdd(loss_acc, red[0]);
}

__global__ void finalize_kernel(const float* __restrict__ loss_acc, float* __restrict__ out_loss) {
    out_loss[0] = 1.25f * loss_acc[0] * (1.0f / 8388608.0f);
}

extern "C" void kernel_launch(void* const* d_in, const int* in_sizes, int n_in,
                              void* d_out, int out_size, void* d_ws, size_t ws_size,
                              hipStream_t stream) {
    const float* x = (const float*)d_in[0];
    const float* W = (const float*)d_in[1];

    float* out      = (float*)d_out;
    float* out_zq   = out;                         // 8388608 f32
    float* out_idx  = out + 8388608;               // 32768 f32
    float* out_loss = out + 8388608 + 32768;       // 1 f32

    // workspace layout
    float* loss_acc = (float*)d_ws;                              // @0
    int*   scount   = (int*)((char*)d_ws + 8);                   // @8
    float* wsq      = (float*)((char*)d_ws + 1024);              // 4 KB
    int*   ws_idx   = (int*)((char*)d_ws + 8192);                // 128 KB
    int*   slist    = (int*)((char*)d_ws + 139264);              // 128 KB
    unsigned short* Wfh = (unsigned short*)((char*)d_ws + 270336);  // 512 KB
    unsigned short* Wfl = (unsigned short*)((char*)d_ws + 794624);  // 512 KB
    float* pws      = (float*)((char*)d_ws + 1318912);           // 3 MB
    const size_t NEEDED = 4464640;

    if (ws_size >= NEEDED) {
        // Zfh/Zfl fragment-major bf16 live in the out_zq region (2 x 16.78 MB);
        // gather overwrites later.
        unsigned short* Zfh = (unsigned short*)out_zq;
        unsigned short* Zfl = Zfh + (size_t)N_ROWS * D_DIM;

        prep_kernel<<<256, 256, 0, stream>>>(W, wsq, Wfh, Wfl, loss_acc, scount);
        convz_kernel<<<2048, 256, 0, stream>>>(x, Zfh, Zfl);
        mm_argmin_kernel<<<2048, 256, 0, stream>>>(Zfh, Zfl, Wfh, Wfl, wsq, pws);
        combine_kernel<<<128, 256, 0, stream>>>(pws, out_idx, ws_idx, scount, slist);
        rescore_kernel<<<256, 256, 0, stream>>>(x, W, wsq, scount, slist, out_idx, ws_idx);
    } else {
        wsq_only_kernel<<<4, 256, 0, stream>>>(W, wsq, loss_acc);
        argmin_f32_kernel<<<N_ROWS / FROWS, 256, 0, stream>>>(x, W, wsq, out_idx, ws_idx);
    }

    gather_loss_kernel<<<2048, 256, 0, stream>>>(x, W, ws_idx, out_zq, loss_acc);
    finalize_kernel<<<1, 1, 0, stream>>>(loss_acc, out_loss);
}